// Round 13
// baseline (2965.154 us; speedup 1.0000x reference)
//
#include <hip/hip_runtime.h>

using f4_t  = __attribute__((ext_vector_type(4))) float;
using f2_t  = __attribute__((ext_vector_type(2))) float;
using bf8_t = __attribute__((ext_vector_type(8))) short;
using u32x4 = __attribute__((ext_vector_type(4))) unsigned int;

#define T_DIM 512
#define B_DIM 256
#define I_DIM 256
#define H_DIM 1024
#define O_DIM 128

// XOR swizzle for GEMM tiles (T2 recipe)
#define SWZ(row, byte) ((byte) ^ (((row) & 7) << 4))
// hT swizzle: 4-bit row XOR (R12-proven: 3x fewer bank conflicts than 3-bit)
#define HSWZ(row, byte) ((byte) ^ (((row) & 15) << 4))

#define SMASK 0x8000800080008000ull  // bf16 sign bits of a 4-element qword

__device__ __forceinline__ unsigned short f2bf(float f) {
  unsigned u = __builtin_bit_cast(unsigned, f);
  return (unsigned short)((u + 0x7FFFu + ((u >> 16) & 1u)) >> 16);
}

__device__ __forceinline__ unsigned long long pack4bf(f4_t v) {
  unsigned long long r;
  r  = (unsigned long long)f2bf(v[0]);
  r |= (unsigned long long)f2bf(v[1]) << 16;
  r |= (unsigned long long)f2bf(v[2]) << 32;
  r |= (unsigned long long)f2bf(v[3]) << 48;
  return r;
}

// ---------------------------------------------------------------- init ------
__global__ __launch_bounds__(256, 1) void k_init(
    const float* __restrict__ Wi, const float* __restrict__ Wh,
    const float* __restrict__ Wo, unsigned short* __restrict__ Wi_b,
    unsigned short* __restrict__ Wh_b, unsigned short* __restrict__ Wo_b,
    unsigned short* __restrict__ hbuf1, unsigned* __restrict__ done) {
  int idx = blockIdx.x * 256 + threadIdx.x;
  int stride = gridDim.x * 256;
  for (int i = idx; i < H_DIM * H_DIM; i += stride) Wh_b[i] = f2bf(Wh[i]);
  for (int i = idx; i < H_DIM * I_DIM; i += stride) Wi_b[i] = f2bf(Wi[i]);
  for (int i = idx; i < O_DIM * H_DIM; i += stride) Wo_b[i] = f2bf(Wo[i]);
  for (int i = idx; i < B_DIM * H_DIM; i += stride) hbuf1[i] = 0x8000;
  for (int i = idx; i < 16 * 32 * 8; i += stride) done[i] = 0;
}

// --------------------------------------------------- phase 1: x @ Wi^T + bi -
__global__ __launch_bounds__(256, 2) void k_inproj(
    const float* __restrict__ x, const unsigned short* __restrict__ Wi_b,
    const float* __restrict__ bi, float* __restrict__ act) {
  __shared__ unsigned short As[128 * 128];
  __shared__ unsigned short Bs[128 * 128];
  int blk = blockIdx.x;
  int mb = (blk & 7) * 128 + (blk >> 6);
  int nb = (blk >> 3) & 7;
  int m0 = mb * 128, n0 = nb * 128;
  int tid = threadIdx.x;
  int lane = tid & 63, w = tid >> 6;
  int wm0 = (w & 1) * 64, wn0 = (w >> 1) * 64;
  int lrow = lane & 15, lk = (lane >> 4) * 8;
  f4_t acc[4][4];
#pragma unroll
  for (int a = 0; a < 4; ++a)
#pragma unroll
    for (int b = 0; b < 4; ++b) acc[a][b] = (f4_t){0.f, 0.f, 0.f, 0.f};

  for (int kb = 0; kb < 2; ++kb) {
    if (kb) __syncthreads();
#pragma unroll
    for (int it = 0; it < 16; ++it) {
      int c = it * 256 + tid;
      int row = c >> 5;
      int kc = (c & 31) * 4;
      f4_t v = *(const f4_t*)(x + (size_t)(m0 + row) * I_DIM + kb * 128 + kc);
      *(unsigned long long*)((char*)As + SWZ(row, row * 256 + kc * 2)) = pack4bf(v);
    }
#pragma unroll
    for (int it = 0; it < 8; ++it) {
      int c = it * 256 + tid;
      int row = c >> 4;
      int k16 = c & 15;
      u32x4 v = *(const u32x4*)(Wi_b + (size_t)(n0 + row) * I_DIM + kb * 128 + k16 * 8);
      *(u32x4*)((char*)Bs + SWZ(row, row * 256 + k16 * 16)) = v;
    }
    __syncthreads();
#pragma unroll
    for (int ks = 0; ks < 4; ++ks) {
      bf8_t aF[4], bF[4];
#pragma unroll
      for (int mt = 0; mt < 4; ++mt) {
        int row = wm0 + mt * 16 + lrow;
        aF[mt] = *(const bf8_t*)((char*)As + SWZ(row, row * 256 + (ks * 32 + lk) * 2));
      }
#pragma unroll
      for (int nt = 0; nt < 4; ++nt) {
        int row = wn0 + nt * 16 + lrow;
        bF[nt] = *(const bf8_t*)((char*)Bs + SWZ(row, row * 256 + (ks * 32 + lk) * 2));
      }
#pragma unroll
      for (int mt = 0; mt < 4; ++mt)
#pragma unroll
        for (int nt = 0; nt < 4; ++nt)
          acc[mt][nt] =
              __builtin_amdgcn_mfma_f32_16x16x32_bf16(aF[mt], bF[nt], acc[mt][nt], 0, 0, 0);
    }
  }
#pragma unroll
  for (int nt = 0; nt < 4; ++nt) {
    int col = n0 + wn0 + nt * 16 + lrow;
    float bv = bi[col];
#pragma unroll
    for (int mt = 0; mt < 4; ++mt) {
      int rbase = m0 + wm0 + mt * 16 + (lane >> 4) * 4;
#pragma unroll
      for (int r = 0; r < 4; ++r)
        act[(size_t)(rbase + r) * H_DIM + col] = acc[mt][nt][r] + bv;
    }
  }
}

// ------------------------------------------------------- phase 2: the scan --
// R13: FULL-OCCUPANCY TWO-CHAIN PIPELINE.  R9's chain (poll -> 32KB IC fetch
// -> compute) is serial; R11 showed 2 chains/WG at HALF occupancy + a missing
// load-wait = 2x loss.  Now: 256 WGs x 256 thr (all CUs), 8 group-pairs x 32
// h-slices of 32 cols.  Chains A=group 2p, B=2p+1 share register-resident Wh.
// Per iteration: pollB+issueB -> vmcnt(8) [A loads ready; B's 8 stay in
// flight] -> process A -> pollA+issueA(t+1) [issued unconditionally so the
// last iteration's vmcnt(8) still retires B's loads] -> vmcnt(8) -> process B.
// Each chain's fetch+flag latency hides under the other chain's compute.
// Protocol unchanged (sign-bit tags = correctness; flags = liveness hints;
// all loads/stores sc0 sc1 via IC -- R12 proved XCD-L2 serves stale lines).
__global__ __launch_bounds__(256, 1) void k_scan(
    const unsigned short* __restrict__ Wh_b, const float* __restrict__ bh,
    float* __restrict__ act, unsigned short* __restrict__ hbuf0,
    unsigned short* __restrict__ hbuf1, unsigned* __restrict__ done) {
  __shared__ __align__(16) char hTA[16 * 2048];
  __shared__ __align__(16) char hTB[16 * 2048];
  __shared__ __align__(16) float pbufA[4][16][36];
  __shared__ __align__(16) float pbufB[4][16][36];
  int blk = blockIdx.x;
  int pp = blk & 7, s = blk >> 3;  // pair, h-slice
  int gA = pp * 2, gB = pp * 2 + 1;
  int b0A = gA * 16, b0B = gB * 16, h0 = s * 32;
  int tid = threadIdx.x;
  int lane = tid & 63, w = tid >> 6;
  int lrow = lane & 15, lgq = lane >> 4;

  // persistent Wh fragments (shared by both chains): 2 n-tiles x 8 k-chunks
  bf8_t Bf[2][8];
#pragma unroll
  for (int n = 0; n < 2; ++n)
#pragma unroll
    for (int kc = 0; kc < 8; ++kc)
      Bf[n][kc] = *(const bf8_t*)(Wh_b + (size_t)(h0 + n * 16 + lrow) * H_DIM +
                                  w * 256 + kc * 32 + lgq * 8);

  int pr = tid >> 4, pc = (tid & 15) * 2;  // pointwise: row pr, 2 cols
  float stA[2] = {0.f, 0.f}, stB[2] = {0.f, 0.f};
  float bhv0 = bh[h0 + pc], bhv1 = bh[h0 + pc + 1];

  unsigned short* hb[2] = {hbuf0, hbuf1};
  unsigned* slotA = done + (gA * 32 + s) * 8;
  unsigned* slotB = done + (gB * 32 + s) * 8;
  const unsigned* pollA = done + (gA * 32 + (lane & 31)) * 8;
  const unsigned* pollB = done + (gB * 32 + (lane & 31)) * 8;
  bool dopoll = (lane < 32) && (lane != s);

  f2_t uA = *(const f2_t*)(act + (size_t)(b0A + pr) * H_DIM + h0 + pc);
  f2_t uB = *(const f2_t*)(act + (size_t)(b0B + pr) * H_DIM + h0 + pc);

  int rh = tid >> 7;            // 0..1 (staging row parity)
  int colb = (tid & 127) * 16;  // staging byte col

  u32x4 qA0, qA1, qA2, qA3, qA4, qA5, qA6, qA7;
  u32x4 qB0, qB1, qB2, qB3, qB4, qB5, qB6, qB7;
  unsigned long long aA, aB;

#define ISSUE8(q0_, q1_, q2_, q3_, q4_, q5_, q6_, q7_, a_)                      \
  asm volatile("global_load_dwordx4 %[d0], %[a0], off sc0 sc1\n\t"              \
               "global_load_dwordx4 %[d1], %[a1], off sc0 sc1\n\t"              \
               "global_load_dwordx4 %[d2], %[a2], off sc0 sc1\n\t"              \
               "global_load_dwordx4 %[d3], %[a3], off sc0 sc1\n\t"              \
               "global_load_dwordx4 %[d4], %[a4], off sc0 sc1\n\t"              \
               "global_load_dwordx4 %[d5], %[a5], off sc0 sc1\n\t"              \
               "global_load_dwordx4 %[d6], %[a6], off sc0 sc1\n\t"              \
               "global_load_dwordx4 %[d7], %[a7], off sc0 sc1"                  \
               : [d0] "=&v"(q0_), [d1] "=&v"(q1_), [d2] "=&v"(q2_),             \
                 [d3] "=&v"(q3_), [d4] "=&v"(q4_), [d5] "=&v"(q5_),             \
                 [d6] "=&v"(q6_), [d7] "=&v"(q7_)                               \
               : [a0] "v"(a_), [a1] "v"(a_ + 4096), [a2] "v"(a_ + 8192),        \
                 [a3] "v"(a_ + 12288), [a4] "v"(a_ + 16384),                    \
                 [a5] "v"(a_ + 20480), [a6] "v"(a_ + 24576),                    \
                 [a7] "v"(a_ + 28672)                                           \
               : "memory")
#define RELOAD(qq, ad)                                                          \
  asm volatile("global_load_dwordx4 %0, %1, off sc0 sc1\n\ts_waitcnt vmcnt(0)"  \
               : "=&v"(qq)                                                      \
               : "v"(ad)                                                        \
               : "memory")
#define STALE(qq, wnt)                                                          \
  ((((qq[0] ^ (wnt)) | (qq[1] ^ (wnt)) | (qq[2] ^ (wnt)) | (qq[3] ^ (wnt))) &   \
    0x80008000u) != 0u)

#define PROC(q0_, q1_, q2_, q3_, q4_, q5_, q6_, q7_, a_, hT_, pbuf_, st_, u_,   \
             b0_, slot_, wnt)                                                   \
  {                                                                             \
    {                                                                           \
      int vg = 0;                                                               \
      for (;;) {                                                                \
        unsigned m = (STALE(q0_, wnt) ? 1u : 0u) | (STALE(q1_, wnt) ? 2u : 0u) |\
                     (STALE(q2_, wnt) ? 4u : 0u) | (STALE(q3_, wnt) ? 8u : 0u) |\
                     (STALE(q4_, wnt) ? 16u : 0u) |                             \
                     (STALE(q5_, wnt) ? 32u : 0u) |                             \
                     (STALE(q6_, wnt) ? 64u : 0u) |                             \
                     (STALE(q7_, wnt) ? 128u : 0u);                             \
        if (m == 0u || ++vg >= 400) break;                                      \
        __builtin_amdgcn_s_sleep(1);                                            \
        if (m & 1u) RELOAD(q0_, a_);                                            \
        if (m & 2u) RELOAD(q1_, a_ + 4096);                                     \
        if (m & 4u) RELOAD(q2_, a_ + 8192);                                     \
        if (m & 8u) RELOAD(q3_, a_ + 12288);                                    \
        if (m & 16u) RELOAD(q4_, a_ + 16384);                                   \
        if (m & 32u) RELOAD(q5_, a_ + 20480);                                   \
        if (m & 64u) RELOAD(q6_, a_ + 24576);                                   \
        if (m & 128u) RELOAD(q7_, a_ + 28672);                                  \
      }                                                                         \
    }                                                                           \
    _Pragma("unroll") for (int d = 0; d < 4; ++d) {                             \
      q0_[d] &= 0x7fff7fffu; q1_[d] &= 0x7fff7fffu; q2_[d] &= 0x7fff7fffu;      \
      q3_[d] &= 0x7fff7fffu; q4_[d] &= 0x7fff7fffu; q5_[d] &= 0x7fff7fffu;      \
      q6_[d] &= 0x7fff7fffu; q7_[d] &= 0x7fff7fffu;                             \
    }                                                                           \
    *(u32x4*)(&hT_[(0 + rh) * 2048 + HSWZ(0 + rh, colb)]) = q0_;                \
    *(u32x4*)(&hT_[(2 + rh) * 2048 + HSWZ(2 + rh, colb)]) = q1_;                \
    *(u32x4*)(&hT_[(4 + rh) * 2048 + HSWZ(4 + rh, colb)]) = q2_;                \
    *(u32x4*)(&hT_[(6 + rh) * 2048 + HSWZ(6 + rh, colb)]) = q3_;                \
    *(u32x4*)(&hT_[(8 + rh) * 2048 + HSWZ(8 + rh, colb)]) = q4_;                \
    *(u32x4*)(&hT_[(10 + rh) * 2048 + HSWZ(10 + rh, colb)]) = q5_;              \
    *(u32x4*)(&hT_[(12 + rh) * 2048 + HSWZ(12 + rh, colb)]) = q6_;              \
    *(u32x4*)(&hT_[(14 + rh) * 2048 + HSWZ(14 + rh, colb)]) = q7_;              \
    asm volatile("s_waitcnt lgkmcnt(0)\ns_barrier" ::: "memory");               \
    __builtin_amdgcn_sched_barrier(0);                                          \
    f4_t acc0 = (f4_t){0.f, 0.f, 0.f, 0.f};                                     \
    f4_t acc1 = (f4_t){0.f, 0.f, 0.f, 0.f};                                     \
    _Pragma("unroll") for (int kc = 0; kc < 8; ++kc) {                          \
      int cbyte = w * 512 + kc * 64 + lgq * 16;                                 \
      bf8_t Af = *(const bf8_t*)(&hT_[lrow * 2048 + HSWZ(lrow, cbyte)]);        \
      acc0 = __builtin_amdgcn_mfma_f32_16x16x32_bf16(Af, Bf[0][kc], acc0, 0, 0, 0); \
      acc1 = __builtin_amdgcn_mfma_f32_16x16x32_bf16(Af, Bf[1][kc], acc1, 0, 0, 0); \
    }                                                                           \
    _Pragma("unroll") for (int r = 0; r < 4; ++r) {                             \
      pbuf_[w][lgq * 4 + r][lrow] = acc0[r];                                    \
      pbuf_[w][lgq * 4 + r][16 + lrow] = acc1[r];                               \
    }                                                                           \
    asm volatile("s_waitcnt lgkmcnt(0)\ns_barrier" ::: "memory");               \
    __builtin_amdgcn_sched_barrier(0);                                          \
    f2_t s0 = *(const f2_t*)&pbuf_[0][pr][pc];                                  \
    f2_t s1 = *(const f2_t*)&pbuf_[1][pr][pc];                                  \
    f2_t s2 = *(const f2_t*)&pbuf_[2][pr][pc];                                  \
    f2_t s3 = *(const f2_t*)&pbuf_[3][pr][pc];                                  \
    float t0 = s0[0] + s1[0] + s2[0] + s3[0] + u_[0] + bhv0;                    \
    float t1 = s0[1] + s1[1] + s2[1] + s3[1] + u_[1] + bhv1;                    \
    st_[0] = st_[0] * 0.8f + t0 * 0.2f;                                         \
    st_[1] = st_[1] * 0.8f + t1 * 0.2f;                                         \
    float h0v = fmaxf(st_[0], 0.f), h1v = fmaxf(st_[1], 0.f);                   \
    unsigned hp = (unsigned)f2bf(h0v) | ((unsigned)f2bf(h1v) << 16);            \
    hp |= (((t >> 1) & 1) ? 0x80008000u : 0u);                                  \
    unsigned long long sa =                                                     \
        (unsigned long long)(hb[par] + (size_t)(b0_ + pr) * H_DIM + h0 + pc);   \
    asm volatile("global_store_dword %0, %1, off sc0 sc1" ::"v"(sa), "v"(hp)    \
                 : "memory");                                                   \
    asm volatile("s_barrier" ::: "memory");                                     \
    if (tid == 0)                                                               \
      __hip_atomic_store(slot_, (unsigned)(t + 1), __ATOMIC_RELAXED,            \
                         __HIP_MEMORY_SCOPE_AGENT);                             \
    f2_t hres2 = (f2_t){h0v, h1v};                                              \
    *(f2_t*)(act + ((size_t)t * B_DIM + b0_ + pr) * H_DIM + h0 + pc) = hres2;   \
    int tn = (t + 1 < T_DIM) ? t + 1 : t;                                       \
    u_ = *(const f2_t*)(act + ((size_t)tn * B_DIM + b0_ + pr) * H_DIM + h0 + pc); \
  }

  // prologue: issue A(0) loads (hb[1] is init-tagged)
  aA = (unsigned long long)((const char*)(hb[1] + (size_t)b0A * H_DIM) + tid * 16);
  ISSUE8(qA0, qA1, qA2, qA3, qA4, qA5, qA6, qA7, aA);

  for (int t = 0; t < T_DIM; ++t) {
    int par = t & 1;
    unsigned want32 = ((((unsigned)(t - 1) >> 1) & 1u) ? 0x80008000u : 0u);

    // ---- phase 1: poll B(t) flags, issue B(t) loads
    if (t > 0 && dopoll) {
      int gd = 0;
      while (__hip_atomic_load(pollB, __ATOMIC_RELAXED, __HIP_MEMORY_SCOPE_AGENT) <
                 (unsigned)t &&
             ++gd < 60000)
        __builtin_amdgcn_s_sleep(1);
    }
    __builtin_amdgcn_sched_barrier(0);
    aB = (unsigned long long)((const char*)(hb[par ^ 1] + (size_t)b0B * H_DIM) +
                              tid * 16);
    ISSUE8(qB0, qB1, qB2, qB3, qB4, qB5, qB6, qB7, aB);

    // ---- phase 2: A loads ready (B's 8 stay in flight); process A(t)
    asm volatile("s_waitcnt vmcnt(8)" ::: "memory");
    __builtin_amdgcn_sched_barrier(0);
    PROC(qA0, qA1, qA2, qA3, qA4, qA5, qA6, qA7, aA, hTA, pbufA, stA, uA, b0A,
         slotA, want32);

    // ---- phase 3: poll A(t+1), issue A(t+1) loads (unconditional issue so
    // the final iteration's vmcnt(8) still retires B's loads)
    if (t + 1 < T_DIM && dopoll) {
      int gd = 0;
      while (__hip_atomic_load(pollA, __ATOMIC_RELAXED, __HIP_MEMORY_SCOPE_AGENT) <
                 (unsigned)(t + 1) &&
             ++gd < 60000)
        __builtin_amdgcn_s_sleep(1);
    }
    __builtin_amdgcn_sched_barrier(0);
    aA = (unsigned long long)((const char*)(hb[par] + (size_t)b0A * H_DIM) + tid * 16);
    ISSUE8(qA0, qA1, qA2, qA3, qA4, qA5, qA6, qA7, aA);

    // ---- phase 4: B loads ready; process B(t)
    asm volatile("s_waitcnt vmcnt(8)" ::: "memory");
    __builtin_amdgcn_sched_barrier(0);
    PROC(qB0, qB1, qB2, qB3, qB4, qB5, qB6, qB7, aB, hTB, pbufB, stB, uB, b0B,
         slotB, want32);
  }
#undef ISSUE8
#undef RELOAD
#undef STALE
#undef PROC
}

// ------------------------------------------------- phase 3: act @ Wo^T + bo -
__global__ __launch_bounds__(256, 2) void k_outproj(
    const float* __restrict__ act, const unsigned short* __restrict__ Wo_b,
    const float* __restrict__ bo, float* __restrict__ out) {
  __shared__ unsigned short As[128 * 64];
  __shared__ unsigned short Bs[128 * 64];
  int m0 = blockIdx.x * 128;
  int tid = threadIdx.x;
  int lane = tid & 63, w = tid >> 6;
  int wm0 = (w & 1) * 64, wn0 = (w >> 1) * 64;
  int lrow = lane & 15, lk = (lane >> 4) * 8;
  f4_t acc[4][4];
#pragma unroll
  for (int a = 0; a < 4; ++a)
#pragma unroll
    for (int b = 0; b < 4; ++b) acc[a][b] = (f4_t){0.f, 0.f, 0.f, 0.f};

  for (int kb = 0; kb < 16; ++kb) {
    if (kb) __syncthreads();
#pragma unroll
    for (int it = 0; it < 8; ++it) {
      int c = it * 256 + tid;
      int row = c >> 4;
      int kc = (c & 15) * 4;
      f4_t v = *(const f4_t*)(act + (size_t)(m0 + row) * H_DIM + kb * 64 + kc);
      *(unsigned long long*)((char*)As + SWZ(row, row * 128 + kc * 2)) = pack4bf(v);
    }
#pragma unroll
    for (int it = 0; it < 4; ++it) {
      int c = it * 256 + tid;
      int row = c >> 3;
      int k16 = c & 7;
      u32x4 v = *(const u32x4*)(Wo_b + (size_t)row * H_DIM + kb * 64 + k16 * 8);
      *(u32x4*)((char*)Bs + SWZ(row, row * 128 + k16 * 16)) = v;
    }
    __syncthreads();
#pragma unroll
    for (int ks = 0; ks < 2; ++ks) {
      bf8_t aF[4], bF[4];
#pragma unroll
      for (int mt = 0; mt < 4; ++mt) {
        int row = wm0 + mt * 16 + lrow;
        aF[mt] = *(const bf8_t*)((char*)As + SWZ(row, row * 128 + (ks * 32 + lk) * 2));
      }
#pragma unroll
      for (int nt = 0; nt < 4; ++nt) {
        int row = wn0 + nt * 16 + lrow;
        bF[nt] = *(const bf8_t*)((char*)Bs + SWZ(row, row * 128 + (ks * 32 + lk) * 2));
      }
#pragma unroll
      for (int mt = 0; mt < 4; ++mt)
#pragma unroll
        for (int nt = 0; nt < 4; ++nt)
          acc[mt][nt] =
              __builtin_amdgcn_mfma_f32_16x16x32_bf16(aF[mt], bF[nt], acc[mt][nt], 0, 0, 0);
    }
  }
#pragma unroll
  for (int nt = 0; nt < 4; ++nt) {
    int col = wn0 + nt * 16 + lrow;
    float bv = bo[col];
#pragma unroll
    for (int mt = 0; mt < 4; ++mt) {
      int rbase = m0 + wm0 + mt * 16 + (lane >> 4) * 4;
#pragma unroll
      for (int r = 0; r < 4; ++r)
        out[(size_t)(rbase + r) * O_DIM + col] = acc[mt][nt][r] + bv;
    }
  }
}

// ---------------------------------------------------------------------------
extern "C" void kernel_launch(void* const* d_in, const int* in_sizes, int n_in,
                              void* d_out, int out_size, void* d_ws, size_t ws_size,
                              hipStream_t stream) {
  const float* x  = (const float*)d_in[0];
  const float* Wi = (const float*)d_in[1];
  const float* bi = (const float*)d_in[2];
  const float* Wh = (const float*)d_in[3];
  const float* bh = (const float*)d_in[4];
  const float* Wo = (const float*)d_in[5];
  const float* bo = (const float*)d_in[6];

  float* out = (float*)d_out;                                  // [T,B,O]
  float* act = out + (size_t)T_DIM * B_DIM * O_DIM;            // [T,B,H]

  char* ws = (char*)d_ws;
  unsigned short* Wh_b  = (unsigned short*)(ws);                               // 2 MB
  unsigned short* Wi_b  = (unsigned short*)(ws + (2u << 20));                  // 512 KB
  unsigned short* Wo_b  = (unsigned short*)(ws + (2u << 20) + (512u << 10));   // 256 KB
  unsigned short* hbuf0 = (unsigned short*)(ws + (2u << 20) + (768u << 10));   // 512 KB
  unsigned short* hbuf1 = (unsigned short*)(ws + (2u << 20) + (1280u << 10));  // 512 KB
  unsigned* done        = (unsigned*)(ws + (2u << 20) + (1792u << 10));        // 16 KB

  k_init<<<1024, 256, 0, stream>>>(Wi, Wh, Wo, Wi_b, Wh_b, Wo_b, hbuf1, done);
  k_inproj<<<8192, 256, 0, stream>>>(x, Wi_b, bi, act);
  k_scan<<<256, 256, 0, stream>>>(Wh_b, bh, act, hbuf0, hbuf1, done);
  k_outproj<<<1024, 256, 0, stream>>>(act, Wo_b, bo, out);
}

// Round 14
// 1565.967 us; speedup vs baseline: 1.8935x; 1.8935x over previous
//
#include <hip/hip_runtime.h>

using f4_t  = __attribute__((ext_vector_type(4))) float;
using f2_t  = __attribute__((ext_vector_type(2))) float;
using bf8_t = __attribute__((ext_vector_type(8))) short;
using u32x4 = __attribute__((ext_vector_type(4))) unsigned int;

#define T_DIM 512
#define B_DIM 256
#define I_DIM 256
#define H_DIM 1024
#define O_DIM 128

// XOR swizzle for GEMM tiles (T2 recipe)
#define SWZ(row, byte) ((byte) ^ (((row) & 7) << 4))
// hT swizzle: 4-bit row XOR (R10/R12-proven)
#define HSWZ(row, byte) ((byte) ^ (((row) & 15) << 4))

__device__ __forceinline__ unsigned short f2bf(float f) {
  unsigned u = __builtin_bit_cast(unsigned, f);
  return (unsigned short)((u + 0x7FFFu + ((u >> 16) & 1u)) >> 16);
}

__device__ __forceinline__ unsigned long long pack4bf(f4_t v) {
  unsigned long long r;
  r  = (unsigned long long)f2bf(v[0]);
  r |= (unsigned long long)f2bf(v[1]) << 16;
  r |= (unsigned long long)f2bf(v[2]) << 32;
  r |= (unsigned long long)f2bf(v[3]) << 48;
  return r;
}

// ---------------------------------------------------------------- init ------
__global__ __launch_bounds__(256, 1) void k_init(
    const float* __restrict__ Wi, const float* __restrict__ Wh,
    const float* __restrict__ Wo, unsigned short* __restrict__ Wi_b,
    unsigned short* __restrict__ Wh_b, unsigned short* __restrict__ Wo_b,
    unsigned short* __restrict__ hbuf1, unsigned* __restrict__ done) {
  int idx = blockIdx.x * 256 + threadIdx.x;
  int stride = gridDim.x * 256;
  for (int i = idx; i < H_DIM * H_DIM; i += stride) Wh_b[i] = f2bf(Wh[i]);
  for (int i = idx; i < H_DIM * I_DIM; i += stride) Wi_b[i] = f2bf(Wi[i]);
  for (int i = idx; i < O_DIM * H_DIM; i += stride) Wo_b[i] = f2bf(Wo[i]);
  for (int i = idx; i < B_DIM * H_DIM; i += stride) hbuf1[i] = 0x8000;
  for (int i = idx; i < 32 * 8 * 8; i += stride) done[i] = 0;
}

// --------------------------------------------------- phase 1: x @ Wi^T + bi -
__global__ __launch_bounds__(256, 2) void k_inproj(
    const float* __restrict__ x, const unsigned short* __restrict__ Wi_b,
    const float* __restrict__ bi, float* __restrict__ act) {
  __shared__ unsigned short As[128 * 128];
  __shared__ unsigned short Bs[128 * 128];
  int blk = blockIdx.x;
  int mb = (blk & 7) * 128 + (blk >> 6);
  int nb = (blk >> 3) & 7;
  int m0 = mb * 128, n0 = nb * 128;
  int tid = threadIdx.x;
  int lane = tid & 63, w = tid >> 6;
  int wm0 = (w & 1) * 64, wn0 = (w >> 1) * 64;
  int lrow = lane & 15, lk = (lane >> 4) * 8;
  f4_t acc[4][4];
#pragma unroll
  for (int a = 0; a < 4; ++a)
#pragma unroll
    for (int b = 0; b < 4; ++b) acc[a][b] = (f4_t){0.f, 0.f, 0.f, 0.f};

  for (int kb = 0; kb < 2; ++kb) {
    if (kb) __syncthreads();
#pragma unroll
    for (int it = 0; it < 16; ++it) {
      int c = it * 256 + tid;
      int row = c >> 5;
      int kc = (c & 31) * 4;
      f4_t v = *(const f4_t*)(x + (size_t)(m0 + row) * I_DIM + kb * 128 + kc);
      *(unsigned long long*)((char*)As + SWZ(row, row * 256 + kc * 2)) = pack4bf(v);
    }
#pragma unroll
    for (int it = 0; it < 8; ++it) {
      int c = it * 256 + tid;
      int row = c >> 4;
      int k16 = c & 15;
      u32x4 v = *(const u32x4*)(Wi_b + (size_t)(n0 + row) * I_DIM + kb * 128 + k16 * 8);
      *(u32x4*)((char*)Bs + SWZ(row, row * 256 + k16 * 16)) = v;
    }
    __syncthreads();
#pragma unroll
    for (int ks = 0; ks < 4; ++ks) {
      bf8_t aF[4], bF[4];
#pragma unroll
      for (int mt = 0; mt < 4; ++mt) {
        int row = wm0 + mt * 16 + lrow;
        aF[mt] = *(const bf8_t*)((char*)As + SWZ(row, row * 256 + (ks * 32 + lk) * 2));
      }
#pragma unroll
      for (int nt = 0; nt < 4; ++nt) {
        int row = wn0 + nt * 16 + lrow;
        bF[nt] = *(const bf8_t*)((char*)Bs + SWZ(row, row * 256 + (ks * 32 + lk) * 2));
      }
#pragma unroll
      for (int mt = 0; mt < 4; ++mt)
#pragma unroll
        for (int nt = 0; nt < 4; ++nt)
          acc[mt][nt] =
              __builtin_amdgcn_mfma_f32_16x16x32_bf16(aF[mt], bF[nt], acc[mt][nt], 0, 0, 0);
    }
  }
#pragma unroll
  for (int nt = 0; nt < 4; ++nt) {
    int col = n0 + wn0 + nt * 16 + lrow;
    float bv = bi[col];
#pragma unroll
    for (int mt = 0; mt < 4; ++mt) {
      int rbase = m0 + wm0 + mt * 16 + (lane >> 4) * 4;
#pragma unroll
      for (int r = 0; r < 4; ++r)
        act[(size_t)(rbase + r) * H_DIM + col] = acc[mt][nt][r] + bv;
    }
  }
}

// ------------------------------------------------------- phase 2: the scan --
// R14: SHRINK THE SLAB.  Cross-round invariant: k_scan time tracks BYTES
// FETCHED PER WG PER STEP (R9 32KB=1198us; R10 32KB=1226; R11/R13 64KB=2.2x;
// chip-wide count irrelevant).  The CU<->IC interface serves a WG's slab at
// throughput, not one RT.  So: re-tile to 8-ROW groups (32 groups x 8 slices
// of 128 cols; 256 WGs x 512 thr, K-split 8, Wh register-resident 128 VGPR).
// Per-WG fetch HALVES to 16KB/step.  MFMA M=8 wastes half each MFMA (util 9%,
// irrelevant).  hT allocated 16 rows; lanes lrow>=8 read unused rows -> only
// unused D-rows affected.  Protocol = R9 verbatim (sign-bit tags, hint flags,
// bounded retry, sc0 sc1 IC path -- R12 proved XCD-L2 is stale).
__global__ __launch_bounds__(512, 1) void k_scan(
    const unsigned short* __restrict__ Wh_b, const float* __restrict__ bh,
    float* __restrict__ act, unsigned short* __restrict__ hbuf0,
    unsigned short* __restrict__ hbuf1, unsigned* __restrict__ done) {
  __shared__ __align__(16) char hT[16 * 2048];     // 8 rows used, 16 alloc'd
  __shared__ __align__(16) float pbuf[8][8][132];  // [k-wave][row][col+pad]
  int blk = blockIdx.x;
  int g = blk & 31, s = blk >> 5;  // 32 groups x 8 h-slices
  int b0 = g * 8, h0 = s * 128;
  int tid = threadIdx.x;
  int lane = tid & 63, w = tid >> 6;  // 8 waves, K-slice w*128..+127
  int lrow = lane & 15, lgq = lane >> 4;

  // persistent Wh fragments: 8 n-tiles x 4 k-chunks (128 VGPR)
  bf8_t Bf[8][4];
#pragma unroll
  for (int n = 0; n < 8; ++n)
#pragma unroll
    for (int kc = 0; kc < 4; ++kc)
      Bf[n][kc] = *(const bf8_t*)(Wh_b + (size_t)(h0 + n * 16 + lrow) * H_DIM +
                                  w * 128 + kc * 32 + lgq * 8);

  int pr = tid >> 6, pc = (tid & 63) * 2;  // pointwise: row pr (0..7), 2 cols
  float st0 = 0.f, st1 = 0.f;
  float bhv0 = bh[h0 + pc], bhv1 = bh[h0 + pc + 1];

  unsigned short* hb[2] = {hbuf0, hbuf1};
  unsigned* myslot = done + (g * 8 + s) * 8;
  const unsigned* pollp = done + (g * 8 + (lane & 7)) * 8;
  bool dopoll = (lane < 8) && (lane != s);

  f2_t ucur = *(const f2_t*)(act + (size_t)(b0 + pr) * H_DIM + h0 + pc);

  int r0 = tid >> 7;            // staging row for q0 (0..3); q1 -> r0+4
  int colb = (tid & 127) * 16;  // staging byte col

#define RELOAD(qq, ad)                                                          \
  asm volatile("global_load_dwordx4 %0, %1, off sc0 sc1\n\ts_waitcnt vmcnt(0)"  \
               : "=&v"(qq)                                                      \
               : "v"(ad)                                                        \
               : "memory")
#define STALE(qq) \
  ((((qq[0] ^ want32) | (qq[1] ^ want32) | (qq[2] ^ want32) | (qq[3] ^ want32)) & \
    0x80008000u) != 0u)

  for (int t = 0; t < T_DIM; ++t) {
    int p = t & 1;
    const unsigned short* hprev = hb[p ^ 1];
    unsigned want32 = ((((unsigned)(t - 1) >> 1) & 1u) ? 0x80008000u : 0u);

    // ---- detect: 8 producer hint flags (4B each)
    if (t > 0 && dopoll) {
      int gd = 0;
      while (__hip_atomic_load(pollp, __ATOMIC_RELAXED, __HIP_MEMORY_SCOPE_AGENT) <
                 (unsigned)t &&
             ++gd < 60000)
        __builtin_amdgcn_s_sleep(1);
    }
    __builtin_amdgcn_sched_barrier(0);

    // ---- fetch once: 16KB slab, 2 coalesced 16B loads/thread
    const char* base = (const char*)(hprev + (size_t)b0 * H_DIM);
    unsigned long long a0 = (unsigned long long)(base + tid * 16);
    u32x4 q0, q1;
    asm volatile(
        "global_load_dwordx4 %[d0], %[a0], off sc0 sc1\n\t"
        "global_load_dwordx4 %[d1], %[a1], off sc0 sc1\n\t"
        "s_waitcnt vmcnt(0)"
        : [d0] "=&v"(q0), [d1] "=&v"(q1)
        : [a0] "v"(a0), [a1] "v"(a0 + 8192)
        : "memory");
    __builtin_amdgcn_sched_barrier(0);

    // prefetch next step's u while validation runs
    int tn = (t + 1 < T_DIM) ? t + 1 : t;
    f2_t unext = *(const f2_t*)(act + ((size_t)tn * B_DIM + b0 + pr) * H_DIM + h0 + pc);

    // ---- validate tags; bounded independent retry
    {
      int vg = 0;
      for (;;) {
        unsigned m = (STALE(q0) ? 1u : 0u) | (STALE(q1) ? 2u : 0u);
        if (m == 0u || ++vg >= 400) break;
        __builtin_amdgcn_s_sleep(1);
        if (m & 1u) RELOAD(q0, a0);
        if (m & 2u) RELOAD(q1, a0 + 8192);
      }
    }
#pragma unroll
    for (int d = 0; d < 4; ++d) {
      q0[d] &= 0x7fff7fffu;
      q1[d] &= 0x7fff7fffu;
    }

    // ---- redistribute into swizzled hT (rows 0..3 from q0, 4..7 from q1)
    *(u32x4*)(&hT[r0 * 2048 + HSWZ(r0, colb)]) = q0;
    *(u32x4*)(&hT[(r0 + 4) * 2048 + HSWZ(r0 + 4, colb)]) = q1;
    asm volatile("s_waitcnt lgkmcnt(0)\ns_barrier" ::: "memory");
    __builtin_amdgcn_sched_barrier(0);

    // ---- MFMA: this wave's K-slice (w*128, 4 chunks), 8 n-tiles
    f4_t acc[8];
#pragma unroll
    for (int n = 0; n < 8; ++n) acc[n] = (f4_t){0.f, 0.f, 0.f, 0.f};
#pragma unroll
    for (int kc = 0; kc < 4; ++kc) {
      int cbyte = w * 256 + kc * 64 + lgq * 16;
      bf8_t Af = *(const bf8_t*)(&hT[lrow * 2048 + HSWZ(lrow, cbyte)]);
#pragma unroll
      for (int n = 0; n < 8; ++n)
        acc[n] = __builtin_amdgcn_mfma_f32_16x16x32_bf16(Af, Bf[n][kc], acc[n], 0, 0, 0);
    }

    // ---- cross-wave K reduction (rows 0..7 only: lanes lgq<2 hold them)
    if (lgq < 2) {
#pragma unroll
      for (int n = 0; n < 8; ++n)
#pragma unroll
        for (int r = 0; r < 4; ++r)
          pbuf[w][lgq * 4 + r][n * 16 + lrow] = acc[n][r];
    }
    asm volatile("s_waitcnt lgkmcnt(0)\ns_barrier" ::: "memory");
    __builtin_amdgcn_sched_barrier(0);

    // ---- pointwise: sum 8 K-partials + u + bh, leaky update, relu
    float t0 = ucur[0] + bhv0, t1 = ucur[1] + bhv1;
#pragma unroll
    for (int k = 0; k < 8; ++k) {
      f2_t sv = *(const f2_t*)&pbuf[k][pr][pc];
      t0 += sv[0];
      t1 += sv[1];
    }
    st0 = st0 * 0.8f + t0 * 0.2f;
    st1 = st1 * 0.8f + t1 * 0.2f;
    float h0v = fmaxf(st0, 0.f), h1v = fmaxf(st1, 0.f);

    // ---- tagged h store (2 cols packed, coalesced dword, fire-and-forget)
    unsigned hp = (unsigned)f2bf(h0v) | ((unsigned)f2bf(h1v) << 16);
    hp |= (((t >> 1) & 1) ? 0x80008000u : 0u);
    unsigned long long sa =
        (unsigned long long)(hb[p] + (size_t)(b0 + pr) * H_DIM + h0 + pc);
    asm volatile("global_store_dword %0, %1, off sc0 sc1" ::"v"(sa), "v"(hp)
                 : "memory");

    asm volatile("s_barrier" ::: "memory");  // stores issued (no ack wait)
    if (tid == 0)
      __hip_atomic_store(myslot, (unsigned)(t + 1), __ATOMIC_RELAXED,
                         __HIP_MEMORY_SCOPE_AGENT);  // hint flag

    f2_t hres2 = (f2_t){h0v, h1v};
    *(f2_t*)(act + ((size_t)t * B_DIM + b0 + pr) * H_DIM + h0 + pc) = hres2;
    ucur = unext;
  }
#undef RELOAD
#undef STALE
}

// ------------------------------------------------- phase 3: act @ Wo^T + bo -
__global__ __launch_bounds__(256, 2) void k_outproj(
    const float* __restrict__ act, const unsigned short* __restrict__ Wo_b,
    const float* __restrict__ bo, float* __restrict__ out) {
  __shared__ unsigned short As[128 * 64];
  __shared__ unsigned short Bs[128 * 64];
  int m0 = blockIdx.x * 128;
  int tid = threadIdx.x;
  int lane = tid & 63, w = tid >> 6;
  int wm0 = (w & 1) * 64, wn0 = (w >> 1) * 64;
  int lrow = lane & 15, lk = (lane >> 4) * 8;
  f4_t acc[4][4];
#pragma unroll
  for (int a = 0; a < 4; ++a)
#pragma unroll
    for (int b = 0; b < 4; ++b) acc[a][b] = (f4_t){0.f, 0.f, 0.f, 0.f};

  for (int kb = 0; kb < 16; ++kb) {
    if (kb) __syncthreads();
#pragma unroll
    for (int it = 0; it < 8; ++it) {
      int c = it * 256 + tid;
      int row = c >> 4;
      int kc = (c & 15) * 4;
      f4_t v = *(const f4_t*)(act + (size_t)(m0 + row) * H_DIM + kb * 64 + kc);
      *(unsigned long long*)((char*)As + SWZ(row, row * 128 + kc * 2)) = pack4bf(v);
    }
#pragma unroll
    for (int it = 0; it < 4; ++it) {
      int c = it * 256 + tid;
      int row = c >> 3;
      int k16 = c & 7;
      u32x4 v = *(const u32x4*)(Wo_b + (size_t)row * H_DIM + kb * 64 + k16 * 8);
      *(u32x4*)((char*)Bs + SWZ(row, row * 128 + k16 * 16)) = v;
    }
    __syncthreads();
#pragma unroll
    for (int ks = 0; ks < 2; ++ks) {
      bf8_t aF[4], bF[4];
#pragma unroll
      for (int mt = 0; mt < 4; ++mt) {
        int row = wm0 + mt * 16 + lrow;
        aF[mt] = *(const bf8_t*)((char*)As + SWZ(row, row * 128 + (ks * 32 + lk) * 2));
      }
#pragma unroll
      for (int nt = 0; nt < 4; ++nt) {
        int row = wn0 + nt * 16 + lrow;
        bF[nt] = *(const bf8_t*)((char*)Bs + SWZ(row, row * 128 + (ks * 32 + lk) * 2));
      }
#pragma unroll
      for (int mt = 0; mt < 4; ++mt)
#pragma unroll
        for (int nt = 0; nt < 4; ++nt)
          acc[mt][nt] =
              __builtin_amdgcn_mfma_f32_16x16x32_bf16(aF[mt], bF[nt], acc[mt][nt], 0, 0, 0);
    }
  }
#pragma unroll
  for (int nt = 0; nt < 4; ++nt) {
    int col = wn0 + nt * 16 + lrow;
    float bv = bo[col];
#pragma unroll
    for (int mt = 0; mt < 4; ++mt) {
      int rbase = m0 + wm0 + mt * 16 + (lane >> 4) * 4;
#pragma unroll
      for (int r = 0; r < 4; ++r)
        out[(size_t)(rbase + r) * O_DIM + col] = acc[mt][nt][r] + bv;
    }
  }
}

// ---------------------------------------------------------------------------
extern "C" void kernel_launch(void* const* d_in, const int* in_sizes, int n_in,
                              void* d_out, int out_size, void* d_ws, size_t ws_size,
                              hipStream_t stream) {
  const float* x  = (const float*)d_in[0];
  const float* Wi = (const float*)d_in[1];
  const float* bi = (const float*)d_in[2];
  const float* Wh = (const float*)d_in[3];
  const float* bh = (const float*)d_in[4];
  const float* Wo = (const float*)d_in[5];
  const float* bo = (const float*)d_in[6];

  float* out = (float*)d_out;                                  // [T,B,O]
  float* act = out + (size_t)T_DIM * B_DIM * O_DIM;            // [T,B,H]

  char* ws = (char*)d_ws;
  unsigned short* Wh_b  = (unsigned short*)(ws);                               // 2 MB
  unsigned short* Wi_b  = (unsigned short*)(ws + (2u << 20));                  // 512 KB
  unsigned short* Wo_b  = (unsigned short*)(ws + (2u << 20) + (512u << 10));   // 256 KB
  unsigned short* hbuf0 = (unsigned short*)(ws + (2u << 20) + (768u << 10));   // 512 KB
  unsigned short* hbuf1 = (unsigned short*)(ws + (2u << 20) + (1280u << 10));  // 512 KB
  unsigned* done        = (unsigned*)(ws + (2u << 20) + (1792u << 10));        // 8 KB

  k_init<<<1024, 256, 0, stream>>>(Wi, Wh, Wo, Wi_b, Wh_b, Wo_b, hbuf1, done);
  k_inproj<<<8192, 256, 0, stream>>>(x, Wi_b, bi, act);
  k_scan<<<256, 512, 0, stream>>>(Wh_b, bh, act, hbuf0, hbuf1, done);
  k_outproj<<<1024, 256, 0, stream>>>(act, Wo_b, bo, out);
}